// Round 1
// baseline (130.365 us; speedup 1.0000x reference)
//
#include <hip/hip_runtime.h>

#define MARGIN 0.3f

typedef __attribute__((ext_vector_type(8))) short short8;
typedef __attribute__((ext_vector_type(4))) short short4v;
typedef __attribute__((ext_vector_type(4))) float floatx4;

// ---- helpers ----------------------------------------------------------------

// order-preserving float->uint encoding so unsigned atomicMin == float min
__device__ __forceinline__ unsigned enc_f32(float f) {
    unsigned u = __float_as_uint(f);
    return (u & 0x80000000u) ? ~u : (u | 0x80000000u);
}
__device__ __forceinline__ float dec_f32(unsigned u) {
    return (u & 0x80000000u) ? __uint_as_float(u & 0x7fffffffu)
                             : __uint_as_float(~u);
}
// fp32 -> bf16 bits, round-to-nearest-even
__device__ __forceinline__ short f2bf(float f) {
    unsigned u = __float_as_uint(f);
    u = u + 0x7fffu + ((u >> 16) & 1u);
    return (short)(u >> 16);
}

// ---- kernel 1: sq2[j] = ||z2[j]||^2 (exact fp32) ----------------------------
__global__ void sq2_kernel(const float* __restrict__ z2, float* __restrict__ sq2) {
    int row  = blockIdx.x * 4 + (threadIdx.x >> 6);
    int lane = threadIdx.x & 63;
    const float* p = z2 + (size_t)row * 128;
    float a = p[lane], b = p[lane + 64];
    float s = a * a + b * b;
    #pragma unroll
    for (int m = 32; m >= 1; m >>= 1) s += __shfl_xor(s, m);
    if (lane == 0) sq2[row] = s;
}

// ---- kernel 2: bf16 MFMA GEMM tile + fused row-min of (sq2[j] - 2*dot) ------
// grid (N/128, N/128), block 256. LDS: 2 x 128x128 bf16 tiles = 64 KiB,
// XOR-swizzled on 16B granules so ds_read_b128 fragment reads are 2-way only.
__global__ __launch_bounds__(256, 2)
void gemm_min_kernel(const float* __restrict__ z1, const float* __restrict__ z2,
                     const float* __restrict__ sq2, unsigned* __restrict__ rowmin)
{
    __shared__ short As[128 * 128];
    __shared__ short Bs[128 * 128];

    const int rt = blockIdx.y, ct = blockIdx.x;
    const int tid = threadIdx.x;

    // K = 128 = full row: each 128x128 fp32 tile is contiguous memory
    const float4* ga = (const float4*)(z1 + (size_t)rt * (128 * 128));
    const float4* gb = (const float4*)(z2 + (size_t)ct * (128 * 128));

    // stage + convert fp32 -> bf16, swizzled: 16B granule g of row r lands at
    // granule (g ^ (r & 15))
    #pragma unroll
    for (int it = 0; it < 16; ++it) {
        int idx  = tid + it * 256;       // 0..4095 float4 positions
        int row  = idx >> 5;             // 32 float4 per row
        int c4   = idx & 31;
        int g16  = c4 >> 1;              // 16B granule (8 bf16)
        int slot = ((g16 ^ (row & 15)) << 3) + ((c4 & 1) << 2); // short offset
        float4 fa = ga[idx];
        float4 fb = gb[idx];
        short4v sa = { f2bf(fa.x), f2bf(fa.y), f2bf(fa.z), f2bf(fa.w) };
        short4v sb = { f2bf(fb.x), f2bf(fb.y), f2bf(fb.z), f2bf(fb.w) };
        *(short4v*)&As[row * 128 + slot] = sa;
        *(short4v*)&Bs[row * 128 + slot] = sb;
    }
    __syncthreads();

    const int w = tid >> 6, lane = tid & 63;
    const int quad = lane >> 4, l15 = lane & 15;
    const int wr = (w >> 1) * 64;        // wave row offset within tile
    const int wc = (w & 1) * 64;         // wave col offset within tile

    floatx4 acc[4][4];
    #pragma unroll
    for (int sm = 0; sm < 4; ++sm)
        #pragma unroll
        for (int sn = 0; sn < 4; ++sn)
            acc[sm][sn] = (floatx4)0.0f;

    // A-frag layout: m = lane&15, k = quad*8 + j (8 contiguous bf16)
    // B-frag layout: n = lane&15, k = quad*8 + j  -> D[m][n] = dot(z1_m, z2_n)
    #pragma unroll
    for (int kk = 0; kk < 4; ++kk) {
        short8 af[4], bfr[4];
        const int g16 = kk * 4 + quad;
        #pragma unroll
        for (int s = 0; s < 4; ++s) {
            int ra = wr + s * 16 + l15;  // ra & 15 == l15
            int rb = wc + s * 16 + l15;
            af[s]  = *(const short8*)&As[ra * 128 + ((g16 ^ l15) << 3)];
            bfr[s] = *(const short8*)&Bs[rb * 128 + ((g16 ^ l15) << 3)];
        }
        #pragma unroll
        for (int sm = 0; sm < 4; ++sm)
            #pragma unroll
            for (int sn = 0; sn < 4; ++sn)
                acc[sm][sn] = __builtin_amdgcn_mfma_f32_16x16x32_bf16(
                    af[sm], bfr[sn], acc[sm][sn], 0, 0, 0);
    }

    // epilogue: val = sq2[j] - 2*dot, mask diagonal, row-min
    float s2[4];
    #pragma unroll
    for (int sn = 0; sn < 4; ++sn)
        s2[sn] = sq2[ct * 128 + wc + sn * 16 + l15];

    __syncthreads();                     // frag reads done -> reuse As
    float* partial = (float*)As;         // [2][128]

    #pragma unroll
    for (int sm = 0; sm < 4; ++sm) {
        #pragma unroll
        for (int reg = 0; reg < 4; ++reg) {
            // C/D layout: col = lane&15, row = quad*4 + reg
            int rowL = wr + sm * 16 + quad * 4 + reg;
            int gi = rt * 128 + rowL;
            float vm = 3.0e38f;
            #pragma unroll
            for (int sn = 0; sn < 4; ++sn) {
                int gj = ct * 128 + wc + sn * 16 + l15;
                float v = s2[sn] - 2.0f * acc[sm][sn][reg];
                v = (gi == gj) ? 3.0e38f : v;   // mask diagonal
                vm = fminf(vm, v);
            }
            #pragma unroll
            for (int m = 8; m >= 1; m >>= 1)    // min across quad's 16 lanes
                vm = fminf(vm, __shfl_xor(vm, m));
            if (l15 == 0) partial[(w & 1) * 128 + rowL] = vm;
        }
    }
    __syncthreads();
    if (tid < 128) {
        float m = fminf(partial[tid], partial[128 + tid]);
        atomicMin(&rowmin[rt * 128 + tid], enc_f32(m));
    }
}

// ---- kernel 3: per-row loss (exact fp32 pos-dist) ---------------------------
__global__ void loss_kernel(const float* __restrict__ z1, const float* __restrict__ z2,
                            const unsigned* __restrict__ rowmin,
                            float* __restrict__ lossv) {
    int i    = blockIdx.x * 4 + (threadIdx.x >> 6);
    int lane = threadIdx.x & 63;
    const float* p1 = z1 + (size_t)i * 128;
    const float* p2 = z2 + (size_t)i * 128;
    float a0 = p1[lane], a1 = p1[lane + 64];
    float b0 = p2[lane], b1 = p2[lane + 64];
    float d0 = a0 - b0, d1 = a1 - b1;
    float pos2 = d0 * d0 + d1 * d1;
    float s1   = a0 * a0 + a1 * a1;
    #pragma unroll
    for (int m = 32; m >= 1; m >>= 1) {
        pos2 += __shfl_xor(pos2, m);
        s1   += __shfl_xor(s1, m);
    }
    if (lane == 0) {
        float neg2 = s1 + dec_f32(rowmin[i]);
        float hard = sqrtf(fmaxf(neg2, 0.0f));
        float pos  = sqrtf(fmaxf(pos2, 0.0f));
        lossv[i] = fmaxf(pos - hard + MARGIN, 0.0f);
    }
}

// ---- kernel 4: mean reduction ----------------------------------------------
__global__ void reduce_kernel(const float* __restrict__ lossv, float* __restrict__ out,
                              int n) {
    __shared__ float sh[4];
    float s = 0.0f;
    for (int i = threadIdx.x; i < n; i += 256) s += lossv[i];
    #pragma unroll
    for (int m = 32; m >= 1; m >>= 1) s += __shfl_xor(s, m);
    if ((threadIdx.x & 63) == 0) sh[threadIdx.x >> 6] = s;
    __syncthreads();
    if (threadIdx.x == 0)
        out[0] = (sh[0] + sh[1] + sh[2] + sh[3]) / (float)n;
}

// ---- launch -----------------------------------------------------------------
extern "C" void kernel_launch(void* const* d_in, const int* in_sizes, int n_in,
                              void* d_out, int out_size, void* d_ws, size_t ws_size,
                              hipStream_t stream) {
    const float* z1 = (const float*)d_in[0];
    const float* z2 = (const float*)d_in[1];
    const int n = in_sizes[0] / 128;            // 8192

    unsigned* rowmin = (unsigned*)d_ws;                       // n * 4 B
    float*    sq2    = (float*)((char*)d_ws + (size_t)n * 4); // n * 4 B
    float*    lossv  = (float*)((char*)d_ws + (size_t)n * 8); // n * 4 B
    float*    out    = (float*)d_out;

    hipMemsetAsync(rowmin, 0xFF, (size_t)n * sizeof(unsigned), stream);
    sq2_kernel<<<n / 4, 256, 0, stream>>>(z2, sq2);
    dim3 grid(n / 128, n / 128);
    gemm_min_kernel<<<grid, 256, 0, stream>>>(z1, z2, sq2, rowmin);
    loss_kernel<<<n / 4, 256, 0, stream>>>(z1, z2, rowmin, lossv);
    reduce_kernel<<<1, 256, 0, stream>>>(lossv, out, n);
}

// Round 3
// 115.356 us; speedup vs baseline: 1.1301x; 1.1301x over previous
//
#include <hip/hip_runtime.h>

#define MARGIN 0.3f

typedef __attribute__((ext_vector_type(8))) short short8;
typedef __attribute__((ext_vector_type(4))) short short4v;
typedef __attribute__((ext_vector_type(4))) float floatx4;

// address-space casts for global_load_lds (direct global->LDS DMA)
#define AS_GLOBAL(p) ((const __attribute__((address_space(1))) char*)(p))
#define AS_LDS(p)    ((__attribute__((address_space(3))) char*)(p))

// ---- helpers ----------------------------------------------------------------

// order-preserving float->uint encoding so unsigned atomicMin == float min
__device__ __forceinline__ unsigned enc_f32(float f) {
    unsigned u = __float_as_uint(f);
    return (u & 0x80000000u) ? ~u : (u | 0x80000000u);
}
__device__ __forceinline__ float dec_f32(unsigned u) {
    return (u & 0x80000000u) ? __uint_as_float(u & 0x7fffffffu)
                             : __uint_as_float(~u);
}
// fp32 -> bf16 bits, round-to-nearest-even
__device__ __forceinline__ short f2bf(float f) {
    unsigned u = __float_as_uint(f);
    u = u + 0x7fffu + ((u >> 16) & 1u);
    return (short)(u >> 16);
}

// ---- kernel 1: prepass ------------------------------------------------------
// fp32 -> bf16 with the LDS XOR swizzle baked into the GLOBAL layout, so the
// gemm kernel can global_load_lds the tile as a flat linear copy.
// Element (row, c): granule g=c/8 stored at row*128 + (g^(row&15))*8 + c%8.
// Also: sq2[row] (exact fp32) and rowmin init.
// grid 1024 x 256: thread = one float4 of z1 + one float4 of z2.
__global__ void prep_kernel(const float* __restrict__ z1, const float* __restrict__ z2,
                            short* __restrict__ z1b, short* __restrict__ z2b,
                            float* __restrict__ sq2, unsigned* __restrict__ rowmin) {
    int idx = blockIdx.x * 256 + threadIdx.x;   // float4 index, 32 per row
    int row = idx >> 5;
    int c4  = idx & 31;
    int g   = c4 >> 1;                          // 16B granule (8 bf16)
    int slot = ((g ^ (row & 15)) << 3) + ((c4 & 1) << 2);
    float4 fa = ((const float4*)z1)[idx];
    float4 fb = ((const float4*)z2)[idx];
    short4v sa = { f2bf(fa.x), f2bf(fa.y), f2bf(fa.z), f2bf(fa.w) };
    short4v sb = { f2bf(fb.x), f2bf(fb.y), f2bf(fb.z), f2bf(fb.w) };
    *(short4v*)&z1b[(size_t)row * 128 + slot] = sa;
    *(short4v*)&z2b[(size_t)row * 128 + slot] = sb;
    // sq2: 32 consecutive lanes own one row (lanes 0-31 / 32-63 of the wave)
    float s = fb.x * fb.x + fb.y * fb.y + fb.z * fb.z + fb.w * fb.w;
    #pragma unroll
    for (int m = 16; m >= 1; m >>= 1) s += __shfl_xor(s, m);
    if (c4 == 0) sq2[row] = s;
    if (threadIdx.x < 8) rowmin[blockIdx.x * 8 + threadIdx.x] = 0xFFFFFFFFu;
}

// ---- kernel 2: bf16 MFMA GEMM tile + fused row-min of (sq2[j] - 2*dot) ------
// grid (N/128, N/128), block 256. LDS: 2 x 128x128 bf16 = 64 KiB (2 blocks/CU).
// Staging via global_load_lds (16B/lane DMA, no VGPR round-trip).
__global__ __launch_bounds__(256, 2)
void gemm_min_kernel(const short* __restrict__ z1b, const short* __restrict__ z2b,
                     const float* __restrict__ sq2, unsigned* __restrict__ rowmin)
{
    __shared__ short As[128 * 128];
    __shared__ short Bs[128 * 128];

    const int rt = blockIdx.y, ct = blockIdx.x;
    const int tid = threadIdx.x;

    const short* gA = z1b + (size_t)rt * 16384;   // 32 KB tile, already swizzled
    const short* gB = z2b + (size_t)ct * 16384;

    // flat linear copy: 8 iters x 256 threads x 16 B = 32 KB per tile.
    // LDS dest = wave-uniform base + lane*16 (contiguous in tid) as required.
    #pragma unroll
    for (int it = 0; it < 8; ++it) {
        int off = it * 2048 + tid * 8;            // shorts
        __builtin_amdgcn_global_load_lds(AS_GLOBAL(gA + off), AS_LDS(As + off), 16, 0, 0);
        __builtin_amdgcn_global_load_lds(AS_GLOBAL(gB + off), AS_LDS(Bs + off), 16, 0, 0);
    }

    const int w = tid >> 6, lane = tid & 63;
    const int quad = lane >> 4, l15 = lane & 15;
    const int wr = (w >> 1) * 64;        // wave row offset within tile
    const int wc = (w & 1) * 64;         // wave col offset within tile

    // sq2 for this wave's columns (independent of LDS; overlaps DMA wait)
    float s2[4];
    #pragma unroll
    for (int sn = 0; sn < 4; ++sn)
        s2[sn] = sq2[ct * 128 + wc + sn * 16 + l15];

    floatx4 acc[4][4];
    #pragma unroll
    for (int sm = 0; sm < 4; ++sm)
        #pragma unroll
        for (int sn = 0; sn < 4; ++sn)
            acc[sm][sn] = (floatx4)0.0f;

    __syncthreads();   // compiler emits s_waitcnt vmcnt(0) -> DMA complete

    // A-frag: m = lane&15, k = quad*8 + j ; B-frag: n = lane&15, same k
    #pragma unroll
    for (int kk = 0; kk < 4; ++kk) {
        short8 af[4], bfr[4];
        const int g16 = kk * 4 + quad;
        #pragma unroll
        for (int s = 0; s < 4; ++s) {
            int ra = wr + s * 16 + l15;
            int rb = wc + s * 16 + l15;
            af[s]  = *(const short8*)&As[ra * 128 + ((g16 ^ l15) << 3)];
            bfr[s] = *(const short8*)&Bs[rb * 128 + ((g16 ^ l15) << 3)];
        }
        #pragma unroll
        for (int sm = 0; sm < 4; ++sm)
            #pragma unroll
            for (int sn = 0; sn < 4; ++sn)
                acc[sm][sn] = __builtin_amdgcn_mfma_f32_16x16x32_bf16(
                    af[sm], bfr[sn], acc[sm][sn], 0, 0, 0);
    }

    // epilogue: val = sq2[j] - 2*dot, mask diagonal, row-min
    __syncthreads();                     // frag reads done -> reuse As
    float* partial = (float*)As;         // [2][128]

    #pragma unroll
    for (int sm = 0; sm < 4; ++sm) {
        #pragma unroll
        for (int reg = 0; reg < 4; ++reg) {
            // C/D layout: col = lane&15, row = quad*4 + reg
            int rowL = wr + sm * 16 + quad * 4 + reg;
            int gi = rt * 128 + rowL;
            float vm = 3.0e38f;
            #pragma unroll
            for (int sn = 0; sn < 4; ++sn) {
                int gj = ct * 128 + wc + sn * 16 + l15;
                float v = s2[sn] - 2.0f * acc[sm][sn][reg];
                v = (gi == gj) ? 3.0e38f : v;   // mask diagonal
                vm = fminf(vm, v);
            }
            #pragma unroll
            for (int m = 8; m >= 1; m >>= 1)    // min across quad's 16 lanes
                vm = fminf(vm, __shfl_xor(vm, m));
            if (l15 == 0) partial[(w & 1) * 128 + rowL] = vm;
        }
    }
    __syncthreads();
    if (tid < 128) {
        float m = fminf(partial[tid], partial[128 + tid]);
        atomicMin(&rowmin[rt * 128 + tid], enc_f32(m));
    }
}

// ---- kernel 3: per-row loss (exact fp32 pos-dist) + block partial sum -------
// grid 256 x 256: each wave handles 8 rows; block writes one partial (32 rows).
__global__ void loss_kernel(const float* __restrict__ z1, const float* __restrict__ z2,
                            const unsigned* __restrict__ rowmin,
                            float* __restrict__ partial) {
    __shared__ float sh[4];
    int w = threadIdx.x >> 6, lane = threadIdx.x & 63;
    int wid = blockIdx.x * 4 + w;        // 0..1023
    float acc = 0.0f;
    #pragma unroll
    for (int k = 0; k < 8; ++k) {
        int i = wid * 8 + k;
        const float* p1 = z1 + (size_t)i * 128;
        const float* p2 = z2 + (size_t)i * 128;
        float a0 = p1[lane], a1 = p1[lane + 64];
        float b0 = p2[lane], b1 = p2[lane + 64];
        float d0 = a0 - b0, d1 = a1 - b1;
        float pos2 = d0 * d0 + d1 * d1;
        float s1   = a0 * a0 + a1 * a1;
        #pragma unroll
        for (int m = 32; m >= 1; m >>= 1) {
            pos2 += __shfl_xor(pos2, m);
            s1   += __shfl_xor(s1, m);
        }
        if (lane == 0) {
            float neg2 = s1 + dec_f32(rowmin[i]);
            float hard = sqrtf(fmaxf(neg2, 0.0f));
            float pos  = sqrtf(fmaxf(pos2, 0.0f));
            acc += fmaxf(pos - hard + MARGIN, 0.0f);
        }
    }
    if (lane == 0) sh[w] = acc;
    __syncthreads();
    if (threadIdx.x == 0)
        partial[blockIdx.x] = sh[0] + sh[1] + sh[2] + sh[3];
}

// ---- kernel 4: final mean — 256 partials, divide by TOTAL ROW COUNT n -------
__global__ void reduce_kernel(const float* __restrict__ partial, float* __restrict__ out,
                              int n) {
    __shared__ float sh[4];
    float s = partial[threadIdx.x];      // 256 threads, 256 partials
    #pragma unroll
    for (int m = 32; m >= 1; m >>= 1) s += __shfl_xor(s, m);
    if ((threadIdx.x & 63) == 0) sh[threadIdx.x >> 6] = s;
    __syncthreads();
    if (threadIdx.x == 0)
        out[0] = (sh[0] + sh[1] + sh[2] + sh[3]) / (float)n;
}

// ---- launch -----------------------------------------------------------------
extern "C" void kernel_launch(void* const* d_in, const int* in_sizes, int n_in,
                              void* d_out, int out_size, void* d_ws, size_t ws_size,
                              hipStream_t stream) {
    const float* z1 = (const float*)d_in[0];
    const float* z2 = (const float*)d_in[1];
    const int n = in_sizes[0] / 128;            // 8192

    char* ws = (char*)d_ws;
    short*    z1b     = (short*)ws;                                   // 2 MB
    short*    z2b     = (short*)(ws + (size_t)n * 128 * 2);           // 2 MB
    float*    sq2     = (float*)(ws + (size_t)n * 128 * 4);           // 32 KB
    unsigned* rowmin  = (unsigned*)(ws + (size_t)n * 128 * 4 + n * 4);
    float*    partial = (float*)(ws + (size_t)n * 128 * 4 + n * 8);   // 1 KB
    float*    out     = (float*)d_out;

    prep_kernel<<<n * 32 / 256, 256, 0, stream>>>(z1, z2, z1b, z2b, sq2, rowmin);
    dim3 grid(n / 128, n / 128);
    gemm_min_kernel<<<grid, 256, 0, stream>>>(z1b, z2b, sq2, rowmin);
    loss_kernel<<<n / 32, 256, 0, stream>>>(z1, z2, rowmin, partial);
    reduce_kernel<<<1, 256, 0, stream>>>(partial, out, n);   // divide by 8192
}